// Round 7
// baseline (1982.624 us; speedup 1.0000x reference)
//
#include <hip/hip_runtime.h>

// KidneyEdgePredictor — edge-GNN. bf16 h-storage + bf16 MFMA matmuls, fp32 gathers.
// N=50000 nodes (D=13), E=1,280,000 edges, H=64.
// encoder(27->64) -> 3x conv(scatter-mean by dst/src) -> MLP 64->64->64->32->1.
//
// R6 post-mortem: k_fill 205us, WRITE 160MB for 10MB payload (16x line
// amplification from random 4B scatter); k_edge LDS-bound at 8 waves/CU.
// R7: (1) bucketed CSR build: scatter packed (node&255)<<24|e into contiguous
//     256-node bucket regions (392 cursors; L2 write-combines the cursor
//     frontier), then per-bucket LDS sort -> coalesced writeback.
// (2) k_edge: epilogue directly in MFMA C-layout (t-gathers by (row,col)),
//     no LDS tile -> occupancy 2x, one less bf16 rounding.
// (3) k_edge_mlp: L4 dot via shfl_xor butterfly (was 8-way-conflicted LDS dot).

#define NN 50000
#define NE 1280000
#define LDP 72               // u16 pitch for mlp LDS tile
#define OFFSZ 50016
#define NB 196               // 256-node buckets: 196*256 = 50176 >= NN
#define SORTCAP 8448         // bucket capacity for k_sort LDS (mean 6554, sd 81)

#define WAVES 2
#define EDGE_ITERS 4
#define EDGE_BLOCKS 2500     // 20000 tiles / (2 waves * 4 iters)

typedef unsigned int   u32;
typedef unsigned short u16;
typedef __attribute__((ext_vector_type(8))) short  short8;   // 8 bf16 (4 VGPRs)
typedef __attribute__((ext_vector_type(4))) float  floatx4;  // MFMA acc

#define MFMA16(a, b, c) __builtin_amdgcn_mfma_f32_16x16x32_bf16(a, b, c, 0, 0, 0)

__device__ __forceinline__ float lrelu(float x) { return x >= 0.0f ? x : 0.2f * x; }
__device__ __forceinline__ float bf2f(u16 u) { return __uint_as_float(((u32)u) << 16); }
__device__ __forceinline__ u16 f2bf(float f) {               // RNE
    u32 b = __float_as_uint(f);
    return (u16)((b + 0x7FFFu + ((b >> 16) & 1u)) >> 16);
}

// B-frag: lane holds B[k0..k0+7][n] of a row-major fp32 weight (ld = row stride)
__device__ __forceinline__ short8 bfrag(const float* __restrict__ W, int ld, int n, int k0) {
    short8 b;
#pragma unroll
    for (int j = 0; j < 8; ++j) b[j] = (short)f2bf(W[(k0 + j) * ld + n]);
    return b;
}

// C(64x64) += A(64x64 from bf16 LDS tile) @ B(frags)
__device__ __forceinline__ void mm_tile(const u16* __restrict__ tb,
                                        const short8 wf[2][4],
                                        floatx4 acc[4][4], int c16, int q4) {
#pragma unroll
    for (int mt = 0; mt < 4; ++mt) {
        const short8 a0 = *(const short8*)(tb + (mt * 16 + c16) * LDP + q4 * 8);
        const short8 a1 = *(const short8*)(tb + (mt * 16 + c16) * LDP + 32 + q4 * 8);
#pragma unroll
        for (int nt = 0; nt < 4; ++nt) {
            acc[mt][nt] = MFMA16(a0, wf[0][nt], acc[mt][nt]);
            acc[mt][nt] = MFMA16(a1, wf[1][nt], acc[mt][nt]);
        }
    }
}

// ---------------- hierarchical CSR scan ----------------
__global__ void __launch_bounds__(256)
k_bsum(const int* __restrict__ deg_in, const int* __restrict__ deg_out,
       int* __restrict__ bsum)
{
    __shared__ int s[256];
    const int tid = threadIdx.x;
    const int i = blockIdx.x * 256 + tid;
#pragma unroll 1
    for (int pass = 0; pass < 2; ++pass) {
        const int* deg = pass ? deg_out : deg_in;
        s[tid] = (i < NN) ? deg[i] : 0;
        __syncthreads();
        for (int d = 128; d > 0; d >>= 1) {
            if (tid < d) s[tid] += s[tid + d];
            __syncthreads();
        }
        if (tid == 0) bsum[pass * NB + blockIdx.x] = s[0];
        __syncthreads();
    }
}

// scan of block sums -> bucket bases; also seeds the bucket scatter cursors
__global__ void __launch_bounds__(256)
k_bscan(const int* __restrict__ bsum, int* __restrict__ boff, int* __restrict__ bcur)
{
    __shared__ int s[256];
    const int tid = threadIdx.x;
#pragma unroll 1
    for (int pass = 0; pass < 2; ++pass) {
        const int v = (tid < NB) ? bsum[pass * NB + tid] : 0;
        s[tid] = v;
        __syncthreads();
        for (int d = 1; d < 256; d <<= 1) {
            const int t = (tid >= d) ? s[tid - d] : 0;
            __syncthreads();
            s[tid] += t;
            __syncthreads();
        }
        if (tid < NB) {
            const int o = s[tid] - v;                  // exclusive
            boff[pass * NB + tid] = o;
            bcur[pass * NB + tid] = o;
        }
        __syncthreads();
    }
}

// block-local scan + bucket base -> per-node off (coalesced)
__global__ void __launch_bounds__(256)
k_bfill(const int* __restrict__ deg_in, const int* __restrict__ deg_out,
        const int* __restrict__ boff,
        int* __restrict__ off_in, int* __restrict__ off_out)
{
    __shared__ int s[256];
    const int tid = threadIdx.x;
    const int i = blockIdx.x * 256 + tid;
#pragma unroll 1
    for (int pass = 0; pass < 2; ++pass) {
        const int* deg = pass ? deg_out : deg_in;
        int* off = pass ? off_out : off_in;
        const int v = (i < NN) ? deg[i] : 0;
        s[tid] = v;
        __syncthreads();
        for (int d = 1; d < 256; d <<= 1) {
            const int t = (tid >= d) ? s[tid - d] : 0;
            __syncthreads();
            s[tid] += t;
            __syncthreads();
        }
        const int o = boff[pass * NB + blockIdx.x] + s[tid] - v;
        if (i < NN) off[i] = o;
        if (i == NN - 1) off[NN] = NE;
        __syncthreads();
    }
}

// bucket scatter: packed (local_node<<24 | e) into contiguous bucket regions.
// Cursor frontier keeps stores clustered -> L2 write-combining (vs R6's 16x).
__global__ void __launch_bounds__(256)
k_fill2(const int* __restrict__ ei, int* __restrict__ bcur,
        int* __restrict__ csr_in, int* __restrict__ csr_out)
{
    const int base = (blockIdx.x * 256 + threadIdx.x) * 4;   // grid = NE/1024
    int s[4], d[4], p[4], q[4];
#pragma unroll
    for (int k = 0; k < 4; ++k) s[k] = ei[base + k];
#pragma unroll
    for (int k = 0; k < 4; ++k) d[k] = ei[NE + base + k];
#pragma unroll
    for (int k = 0; k < 4; ++k) p[k] = atomicAdd(&bcur[NB + (s[k] >> 8)], 1); // out
#pragma unroll
    for (int k = 0; k < 4; ++k) q[k] = atomicAdd(&bcur[d[k] >> 8], 1);        // in
#pragma unroll
    for (int k = 0; k < 4; ++k) csr_out[p[k]] = ((s[k] & 255) << 24) | (base + k);
#pragma unroll
    for (int k = 0; k < 4; ++k) csr_in[q[k]] = ((d[k] & 255) << 24) | (base + k);
}

// per-bucket sort into exact per-node order (LDS counting sort), in place
__global__ void __launch_bounds__(256)
k_sort(int* __restrict__ csr, const int* __restrict__ off)
{
    __shared__ int cur[256];
    __shared__ int outbuf[SORTCAP];
    const int tid = threadIdx.x;
    const int n0 = blockIdx.x * 256;
    const int nn = min(256, NN - n0);
    const int base = off[n0];
    const int end  = off[n0 + nn];
    const int L = end - base;
    if (tid < nn) cur[tid] = off[n0 + tid] - base;
    __syncthreads();
    for (int i = tid; i < L; i += 256) {
        const u32 v = (u32)csr[base + i];
        const int loc = v >> 24;
        const int e = v & 0xFFFFFF;
        const int pos = atomicAdd(&cur[loc], 1);
        if (pos < SORTCAP) outbuf[pos] = e;
    }
    __syncthreads();
    for (int i = tid; i < L; i += 256) csr[base + i] = outbuf[i];
}

// ---------------- encoder (+ degree histogram) ----------------
__global__ void __launch_bounds__(128)
k_enc(const float* __restrict__ x, const int* __restrict__ ei,
      const float* __restrict__ raw, const float* __restrict__ wenc,
      const float* __restrict__ benc, u16* __restrict__ hm,
      int* __restrict__ deg_in, int* __restrict__ deg_out)
{
    __shared__ alignas(16) u16 tile[WAVES][64 * LDP];
    const int w = threadIdx.x >> 6, lane = threadIdx.x & 63;

    for (int it = 0; it < EDGE_ITERS; ++it) {
        const int tileId = (it * EDGE_BLOCKS + blockIdx.x) * WAVES + w;
        const int e0 = tileId * 64;

        const int ms = ei[e0 + lane];
        const int md = ei[NE + e0 + lane];
        atomicAdd(&deg_out[ms], 1);                    // fused histogram
        atomicAdd(&deg_in[md], 1);

        float f[27];
#pragma unroll
        for (int j = 0; j < 13; ++j) f[j]      = x[ms * 13 + j];
#pragma unroll
        for (int j = 0; j < 13; ++j) f[13 + j] = x[md * 13 + j];
        f[26] = raw[e0 + lane];

        float acc[64];
#pragma unroll
        for (int c = 0; c < 64; ++c) acc[c] = benc[c];
        for (int k = 0; k < 27; ++k) {
            const float vk = f[k];
#pragma unroll
            for (int c = 0; c < 64; ++c) acc[c] += vk * wenc[k * 64 + c];
        }
#pragma unroll
        for (int c = 0; c < 64; ++c) tile[w][lane * LDP + c] = f2bf(lrelu(acc[c]));
        // wave-private LDS, lockstep wave64: no barrier. channel-major store.
        for (int i = 0; i < 64; ++i)
            hm[(size_t)(e0 + i) * 64 + lane] = tile[w][i * LDP + lane];
    }
}

// ---------------- per-node aggregate + transform: t = mean(h rows) @ W ----------------
__global__ void __launch_bounds__(256)
k_agg(const u16* __restrict__ hm,
      const int* __restrict__ off_in, const int* __restrict__ csr_in,
      const int* __restrict__ off_out, const int* __restrict__ csr_out,
      const float* __restrict__ w_in, const float* __restrict__ w_out,
      float* __restrict__ t_in, float* __restrict__ t_out)
{
    __shared__ float m[4][64];
    const int w = threadIdx.x >> 6, lane = threadIdx.x & 63;
    const int node = blockIdx.x * 4 + w;               // grid*4 == NN exactly
    const int rg = lane >> 3;                          // row slot in 8-batch
    const int co = (lane & 7) * 8;                     // channel octet base

    for (int pass = 0; pass < 2; ++pass) {
        const int* off = pass ? off_out : off_in;
        const int* csr = pass ? csr_out : csr_in;
        const float* wp = pass ? w_out : w_in;
        float* tp       = pass ? t_out : t_in;

        const int b0 = off[node], b1 = off[node + 1];
        float fa[8], fb[8];
#pragma unroll
        for (int c = 0; c < 8; ++c) { fa[c] = 0.f; fb[c] = 0.f; }

        int j = b0;
        for (; j + 16 <= b1; j += 16) {                // 16 rows in flight
            const int ea = csr[j + rg];
            const int eb = csr[j + 8 + rg];
            const short8 va = *(const short8*)(hm + (size_t)ea * 64 + co);
            const short8 vb = *(const short8*)(hm + (size_t)eb * 64 + co);
#pragma unroll
            for (int c = 0; c < 8; ++c) fa[c] += bf2f((u16)va[c]);
#pragma unroll
            for (int c = 0; c < 8; ++c) fb[c] += bf2f((u16)vb[c]);
        }
        for (; j < b1; j += 8) {                       // tail, predicated
            const int jj = j + rg;
            const int idx = jj < b1 ? jj : b0;
            const float fl = jj < b1 ? 1.f : 0.f;
            const int e = csr[idx];
            const short8 v = *(const short8*)(hm + (size_t)e * 64 + co);
#pragma unroll
            for (int c = 0; c < 8; ++c) fa[c] += fl * bf2f((u16)v[c]);
        }
#pragma unroll
        for (int c = 0; c < 8; ++c) fa[c] += fb[c];
#pragma unroll
        for (int d = 8; d < 64; d <<= 1)
#pragma unroll
            for (int c = 0; c < 8; ++c) fa[c] += __shfl_xor(fa[c], d, 64);

        const int deg = b1 - b0;
        const float inv = 1.0f / (float)(deg > 0 ? deg : 1);
        if (lane < 8) {
#pragma unroll
            for (int c = 0; c < 8; ++c) m[w][lane * 8 + c] = fa[c] * inv;
        }
        float acc = 0.f;
        for (int k = 0; k < 64; ++k) acc += m[w][k] * wp[k * 64 + lane];
        tp[(size_t)node * 64 + lane] = acc;
    }
}

// ---------------- conv edge update (layers 1,2), MFMA, no LDS tile ----------------
// epilogue in C-layout: per mt-block, gather t rows by (row=mt*16+q4*4+r,
// col=nt*16+c16), add bias + t, lrelu, store u16 directly (one rounding only).
__global__ void __launch_bounds__(128, 4)
k_edge(const float* __restrict__ wself, const float* __restrict__ bself,
       const float* __restrict__ t_in, const float* __restrict__ t_out,
       const int* __restrict__ ei, u16* __restrict__ hm)
{
    __shared__ int sidx[WAVES][64], didx[WAVES][64];
    const int w = threadIdx.x >> 6, lane = threadIdx.x & 63;
    const int c16 = lane & 15, q4 = lane >> 4;

    short8 wf[2][4];                                   // Wself bf16 frags, resident
    float bias[4];
#pragma unroll
    for (int ks = 0; ks < 2; ++ks)
#pragma unroll
        for (int nt = 0; nt < 4; ++nt)
            wf[ks][nt] = bfrag(wself, 64, nt * 16 + c16, ks * 32 + q4 * 8);
#pragma unroll
    for (int nt = 0; nt < 4; ++nt) bias[nt] = bself[nt * 16 + c16];

    for (int it = 0; it < EDGE_ITERS; ++it) {
        const int tileId = (it * EDGE_BLOCKS + blockIdx.x) * WAVES + w;
        const int e0 = tileId * 64;
        sidx[w][lane] = ei[e0 + lane];                 // wave-private, lockstep
        didx[w][lane] = ei[NE + e0 + lane];

#pragma unroll
        for (int mt = 0; mt < 4; ++mt) {
            // A-frags for rows mt*16+c16 (disjoint from rows stored below)
            const short8* ap = (const short8*)(hm + (size_t)(e0 + mt * 16 + c16) * 64 + q4 * 8);
            const short8 a0 = ap[0];
            const short8 a1 = ap[4];
            floatx4 acc[4];
#pragma unroll
            for (int nt = 0; nt < 4; ++nt) acc[nt] = (floatx4)(0.0f);
#pragma unroll
            for (int nt = 0; nt < 4; ++nt) {
                acc[nt] = MFMA16(a0, wf[0][nt], acc[nt]);
                acc[nt] = MFMA16(a1, wf[1][nt], acc[nt]);
            }
            // t gathers for rows mt*16+q4*4+r (C-layout rows of this wave)
            float tv[4][4], uv[4][4];
#pragma unroll
            for (int r = 0; r < 4; ++r) {
                const int s = sidx[w][mt * 16 + q4 * 4 + r];
#pragma unroll
                for (int nt = 0; nt < 4; ++nt)
                    tv[r][nt] = t_in[(size_t)s * 64 + nt * 16 + c16];
            }
#pragma unroll
            for (int r = 0; r < 4; ++r) {
                const int d = didx[w][mt * 16 + q4 * 4 + r];
#pragma unroll
                for (int nt = 0; nt < 4; ++nt)
                    uv[r][nt] = t_out[(size_t)d * 64 + nt * 16 + c16];
            }
#pragma unroll
            for (int nt = 0; nt < 4; ++nt)
#pragma unroll
                for (int r = 0; r < 4; ++r) {
                    const int row = mt * 16 + q4 * 4 + r;
                    const float v = acc[nt][r] + bias[nt] + tv[r][nt] + uv[r][nt];
                    hm[(size_t)(e0 + row) * 64 + nt * 16 + c16] = f2bf(lrelu(v));
                }
        }
    }
}

// ---------------- conv3 + MLP head fused, MFMA ----------------
__global__ void __launch_bounds__(128, 2)
k_edge_mlp(const float* __restrict__ wself, const float* __restrict__ bself,
           const float* __restrict__ t_in, const float* __restrict__ t_out,
           const int* __restrict__ ei, const u16* __restrict__ hm,
           const float* __restrict__ w1, const float* __restrict__ b1,
           const float* __restrict__ w2, const float* __restrict__ b2,
           const float* __restrict__ w3, const float* __restrict__ b3,
           const float* __restrict__ w4, const float* __restrict__ b4,
           float* __restrict__ out)
{
    __shared__ alignas(16) u16 tile[WAVES][64 * LDP];
    __shared__ int sidx[WAVES][64], didx[WAVES][64];
    const int w = threadIdx.x >> 6, lane = threadIdx.x & 63;
    const int c16 = lane & 15, q4 = lane >> 4;

    short8 wfS[2][4], wf1[2][4], wf2[2][4], wf3[2][2];
    float bS[4], bv1[4], bv2[4], bv3[2];
#pragma unroll
    for (int ks = 0; ks < 2; ++ks) {
#pragma unroll
        for (int nt = 0; nt < 4; ++nt) {
            wfS[ks][nt] = bfrag(wself, 64, nt * 16 + c16, ks * 32 + q4 * 8);
            wf1[ks][nt] = bfrag(w1,    64, nt * 16 + c16, ks * 32 + q4 * 8);
            wf2[ks][nt] = bfrag(w2,    64, nt * 16 + c16, ks * 32 + q4 * 8);
        }
#pragma unroll
        for (int nt = 0; nt < 2; ++nt)
            wf3[ks][nt] = bfrag(w3, 32, nt * 16 + c16, ks * 32 + q4 * 8);
    }
#pragma unroll
    for (int nt = 0; nt < 4; ++nt) { bS[nt] = bself[nt*16+c16]; bv1[nt] = b1[nt*16+c16]; bv2[nt] = b2[nt*16+c16]; }
#pragma unroll
    for (int nt = 0; nt < 2; ++nt) bv3[nt] = b3[nt * 16 + c16];
    const float w4a = w4[c16], w4b = w4[16 + c16], b4v = b4[0];

    for (int it = 0; it < EDGE_ITERS; ++it) {
        const int tileId = (it * EDGE_BLOCKS + blockIdx.x) * WAVES + w;
        const int e0 = tileId * 64;
        sidx[w][lane] = ei[e0 + lane];
        didx[w][lane] = ei[NE + e0 + lane];

        // conv3: MFMA + direct t-add in C-layout, h3 -> LDS tile (one rounding)
#pragma unroll
        for (int mt = 0; mt < 4; ++mt) {
            const short8* ap = (const short8*)(hm + (size_t)(e0 + mt * 16 + c16) * 64 + q4 * 8);
            const short8 a0 = ap[0];
            const short8 a1 = ap[4];
            floatx4 acc[4];
#pragma unroll
            for (int nt = 0; nt < 4; ++nt) acc[nt] = (floatx4)(0.0f);
#pragma unroll
            for (int nt = 0; nt < 4; ++nt) {
                acc[nt] = MFMA16(a0, wfS[0][nt], acc[nt]);
                acc[nt] = MFMA16(a1, wfS[1][nt], acc[nt]);
            }
            float tv[4][4], uv[4][4];
#pragma unroll
            for (int r = 0; r < 4; ++r) {
                const int s = sidx[w][mt * 16 + q4 * 4 + r];
#pragma unroll
                for (int nt = 0; nt < 4; ++nt)
                    tv[r][nt] = t_in[(size_t)s * 64 + nt * 16 + c16];
            }
#pragma unroll
            for (int r = 0; r < 4; ++r) {
                const int d = didx[w][mt * 16 + q4 * 4 + r];
#pragma unroll
                for (int nt = 0; nt < 4; ++nt)
                    uv[r][nt] = t_out[(size_t)d * 64 + nt * 16 + c16];
            }
#pragma unroll
            for (int nt = 0; nt < 4; ++nt)
#pragma unroll
                for (int r = 0; r < 4; ++r) {
                    const int row = mt * 16 + q4 * 4 + r;
                    const float v = acc[nt][r] + bS[nt] + tv[r][nt] + uv[r][nt];
                    tile[w][row * LDP + nt * 16 + c16] = f2bf(lrelu(v));
                }
        }

        floatx4 acc[4][4];
        // MLP L1 (tile -> tile)
#pragma unroll
        for (int mt = 0; mt < 4; ++mt)
#pragma unroll
            for (int nt = 0; nt < 4; ++nt) acc[mt][nt] = (floatx4)(0.0f);
        mm_tile(tile[w], wf1, acc, c16, q4);
#pragma unroll
        for (int mt = 0; mt < 4; ++mt)
#pragma unroll
            for (int nt = 0; nt < 4; ++nt)
#pragma unroll
                for (int r = 0; r < 4; ++r)
                    tile[w][(mt * 16 + q4 * 4 + r) * LDP + nt * 16 + c16] =
                        f2bf(lrelu(acc[mt][nt][r] + bv1[nt]));

        // MLP L2
#pragma unroll
        for (int mt = 0; mt < 4; ++mt)
#pragma unroll
            for (int nt = 0; nt < 4; ++nt) acc[mt][nt] = (floatx4)(0.0f);
        mm_tile(tile[w], wf2, acc, c16, q4);
#pragma unroll
        for (int mt = 0; mt < 4; ++mt)
#pragma unroll
            for (int nt = 0; nt < 4; ++nt)
#pragma unroll
                for (int r = 0; r < 4; ++r)
                    tile[w][(mt * 16 + q4 * 4 + r) * LDP + nt * 16 + c16] =
                        f2bf(lrelu(acc[mt][nt][r] + bv2[nt]));

        // MLP L3: 64 -> 32 (acc in registers)
        floatx4 a3[4][2];
#pragma unroll
        for (int mt = 0; mt < 4; ++mt)
#pragma unroll
            for (int nt = 0; nt < 2; ++nt) a3[mt][nt] = (floatx4)(0.0f);
#pragma unroll
        for (int mt = 0; mt < 4; ++mt) {
            const short8 a0 = *(const short8*)(tile[w] + (mt * 16 + c16) * LDP + q4 * 8);
            const short8 a1 = *(const short8*)(tile[w] + (mt * 16 + c16) * LDP + 32 + q4 * 8);
#pragma unroll
            for (int nt = 0; nt < 2; ++nt) {
                a3[mt][nt] = MFMA16(a0, wf3[0][nt], a3[mt][nt]);
                a3[mt][nt] = MFMA16(a1, wf3[1][nt], a3[mt][nt]);
            }
        }
        // MLP L4 in registers: butterfly over c16 (no LDS, no bank conflicts)
#pragma unroll
        for (int mt = 0; mt < 4; ++mt)
#pragma unroll
            for (int r = 0; r < 4; ++r) {
                float p = lrelu(a3[mt][0][r] + bv3[0]) * w4a
                        + lrelu(a3[mt][1][r] + bv3[1]) * w4b;
                p += __shfl_xor(p, 1, 64);
                p += __shfl_xor(p, 2, 64);
                p += __shfl_xor(p, 4, 64);
                p += __shfl_xor(p, 8, 64);
                if (c16 == 0) out[e0 + mt * 16 + q4 * 4 + r] = p + b4v;
            }
    }
}

extern "C" void kernel_launch(void* const* d_in, const int* in_sizes, int n_in,
                              void* d_out, int out_size, void* d_ws, size_t ws_size,
                              hipStream_t stream)
{
    const float* x      = (const float*)d_in[0];
    const int*   ei     = (const int*)  d_in[1];
    const float* raw    = (const float*)d_in[2];
    const float* wenc   = (const float*)d_in[3];
    const float* benc   = (const float*)d_in[4];
    const float* wself1 = (const float*)d_in[5];
    const float* bself1 = (const float*)d_in[6];
    const float* win1   = (const float*)d_in[7];
    const float* wout1  = (const float*)d_in[8];
    const float* wself2 = (const float*)d_in[9];
    const float* bself2 = (const float*)d_in[10];
    const float* win2   = (const float*)d_in[11];
    const float* wout2  = (const float*)d_in[12];
    const float* wself3 = (const float*)d_in[13];
    const float* bself3 = (const float*)d_in[14];
    const float* win3   = (const float*)d_in[15];
    const float* wout3  = (const float*)d_in[16];
    const float* w1 = (const float*)d_in[17]; const float* b1 = (const float*)d_in[18];
    const float* w2 = (const float*)d_in[19]; const float* b2 = (const float*)d_in[20];
    const float* w3 = (const float*)d_in[21]; const float* b3 = (const float*)d_in[22];
    const float* w4 = (const float*)d_in[23]; const float* b4 = (const float*)d_in[24];

    // ws layout: t_in|t_out (fp32) · deg/off/csr/bsum/boff/bcur (int) · hm (bf16)
    float* t_in    = (float*)d_ws;
    float* t_out   = t_in + (size_t)NN * 64;
    int*   deg_in  = (int*)(t_out + (size_t)NN * 64);
    int*   deg_out = deg_in + NN;
    int*   off_in  = deg_out + NN;
    int*   off_out = off_in + OFFSZ;
    int*   csr_in  = off_out + OFFSZ;
    int*   csr_out = csr_in + NE;
    int*   bsum    = csr_out + NE;                     // 2*NB ints (512-pad)
    int*   boff    = bsum + 512;
    int*   bcur    = boff + 512;
    u16*   hm      = (u16*)(bcur + 512);               // 16B-aligned

    hipMemsetAsync(deg_in, 0, (size_t)2 * NN * sizeof(int), stream);

    // encoder + fused degree histogram
    k_enc<<<EDGE_BLOCKS, 128, 0, stream>>>(x, ei, raw, wenc, benc, hm, deg_in, deg_out);

    // hierarchical scan + bucketed CSR build
    k_bsum <<<NB, 256, 0, stream>>>(deg_in, deg_out, bsum);
    k_bscan<<<1,  256, 0, stream>>>(bsum, boff, bcur);
    k_bfill<<<NB, 256, 0, stream>>>(deg_in, deg_out, boff, off_in, off_out);
    k_fill2<<<NE / 1024, 256, 0, stream>>>(ei, bcur, csr_in, csr_out);
    k_sort<<<NB, 256, 0, stream>>>(csr_in, off_in);
    k_sort<<<NB, 256, 0, stream>>>(csr_out, off_out);

    k_agg<<<NN / 4, 256, 0, stream>>>(hm, off_in, csr_in, off_out, csr_out,
                                      win1, wout1, t_in, t_out);
    k_edge<<<EDGE_BLOCKS, 128, 0, stream>>>(wself1, bself1, t_in, t_out, ei, hm);

    k_agg<<<NN / 4, 256, 0, stream>>>(hm, off_in, csr_in, off_out, csr_out,
                                      win2, wout2, t_in, t_out);
    k_edge<<<EDGE_BLOCKS, 128, 0, stream>>>(wself2, bself2, t_in, t_out, ei, hm);

    k_agg<<<NN / 4, 256, 0, stream>>>(hm, off_in, csr_in, off_out, csr_out,
                                      win3, wout3, t_in, t_out);
    k_edge_mlp<<<EDGE_BLOCKS, 128, 0, stream>>>(wself3, bself3, t_in, t_out, ei, hm,
                                                w1, b1, w2, b2, w3, b3, w4, b4,
                                                (float*)d_out);
}

// Round 8
// 1068.152 us; speedup vs baseline: 1.8561x; 1.8561x over previous
//
#include <hip/hip_runtime.h>

// KidneyEdgePredictor — edge-GNN. bf16 h-storage + bf16 MFMA matmuls, fp32 gathers.
// N=50000 nodes (D=13), E=1,280,000 edges, H=64.
// encoder(27->64) -> 3x conv(scatter-mean by dst/src) -> MLP 64->64->64->32->1.
//
// R7 post-mortem: bucketed fill REGRESSED (392 hot cursors -> ~6.5K serialized
// atomics each -> 1051us vs 205us). Per-node cursors (100K addresses, ~26
// atomics each) win despite 16x line amplification. R8: revert to R6's k_fill
// (now 8-wide ILP); keep R7's k_edge / k_edge_mlp (C-layout epilogue, no LDS
// tile in k_edge, butterfly L4) — measured net-neutral and they free LDS.

#define NN 50000
#define NE 1280000
#define LDP 72               // u16 pitch for mlp LDS tile
#define OFFSZ 50016
#define NB 196               // scan blocks: 196*256 = 50176 >= NN

#define WAVES 2
#define EDGE_ITERS 4
#define EDGE_BLOCKS 2500     // 20000 tiles / (2 waves * 4 iters)

typedef unsigned int   u32;
typedef unsigned short u16;
typedef __attribute__((ext_vector_type(8))) short  short8;   // 8 bf16 (4 VGPRs)
typedef __attribute__((ext_vector_type(4))) float  floatx4;  // MFMA acc

#define MFMA16(a, b, c) __builtin_amdgcn_mfma_f32_16x16x32_bf16(a, b, c, 0, 0, 0)

__device__ __forceinline__ float lrelu(float x) { return x >= 0.0f ? x : 0.2f * x; }
__device__ __forceinline__ float bf2f(u16 u) { return __uint_as_float(((u32)u) << 16); }
__device__ __forceinline__ u16 f2bf(float f) {               // RNE
    u32 b = __float_as_uint(f);
    return (u16)((b + 0x7FFFu + ((b >> 16) & 1u)) >> 16);
}

// B-frag: lane holds B[k0..k0+7][n] of a row-major fp32 weight (ld = row stride)
__device__ __forceinline__ short8 bfrag(const float* __restrict__ W, int ld, int n, int k0) {
    short8 b;
#pragma unroll
    for (int j = 0; j < 8; ++j) b[j] = (short)f2bf(W[(k0 + j) * ld + n]);
    return b;
}

// C(64x64) += A(64x64 from bf16 LDS tile) @ B(frags)
__device__ __forceinline__ void mm_tile(const u16* __restrict__ tb,
                                        const short8 wf[2][4],
                                        floatx4 acc[4][4], int c16, int q4) {
#pragma unroll
    for (int mt = 0; mt < 4; ++mt) {
        const short8 a0 = *(const short8*)(tb + (mt * 16 + c16) * LDP + q4 * 8);
        const short8 a1 = *(const short8*)(tb + (mt * 16 + c16) * LDP + 32 + q4 * 8);
#pragma unroll
        for (int nt = 0; nt < 4; ++nt) {
            acc[mt][nt] = MFMA16(a0, wf[0][nt], acc[mt][nt]);
            acc[mt][nt] = MFMA16(a1, wf[1][nt], acc[mt][nt]);
        }
    }
}

// ---------------- hierarchical CSR scan ----------------
__global__ void __launch_bounds__(256)
k_bsum(const int* __restrict__ deg_in, const int* __restrict__ deg_out,
       int* __restrict__ bsum)
{
    __shared__ int s[256];
    const int tid = threadIdx.x;
    const int i = blockIdx.x * 256 + tid;
#pragma unroll 1
    for (int pass = 0; pass < 2; ++pass) {
        const int* deg = pass ? deg_out : deg_in;
        s[tid] = (i < NN) ? deg[i] : 0;
        __syncthreads();
        for (int d = 128; d > 0; d >>= 1) {
            if (tid < d) s[tid] += s[tid + d];
            __syncthreads();
        }
        if (tid == 0) bsum[pass * NB + blockIdx.x] = s[0];
        __syncthreads();
    }
}

__global__ void __launch_bounds__(256)
k_bscan(const int* __restrict__ bsum, int* __restrict__ boff)
{
    __shared__ int s[256];
    const int tid = threadIdx.x;
#pragma unroll 1
    for (int pass = 0; pass < 2; ++pass) {
        const int v = (tid < NB) ? bsum[pass * NB + tid] : 0;
        s[tid] = v;
        __syncthreads();
        for (int d = 1; d < 256; d <<= 1) {
            const int t = (tid >= d) ? s[tid - d] : 0;
            __syncthreads();
            s[tid] += t;
            __syncthreads();
        }
        if (tid < NB) boff[pass * NB + tid] = s[tid] - v;   // exclusive
        __syncthreads();
    }
}

// block-local scan + block offset -> off & cur (coalesced)
__global__ void __launch_bounds__(256)
k_bfill(const int* __restrict__ deg_in, const int* __restrict__ deg_out,
        const int* __restrict__ boff,
        int* __restrict__ off_in, int* __restrict__ off_out,
        int* __restrict__ cur_in, int* __restrict__ cur_out)
{
    __shared__ int s[256];
    const int tid = threadIdx.x;
    const int i = blockIdx.x * 256 + tid;
#pragma unroll 1
    for (int pass = 0; pass < 2; ++pass) {
        const int* deg = pass ? deg_out : deg_in;
        int* off = pass ? off_out : off_in;
        int* cur = pass ? cur_out : cur_in;
        const int v = (i < NN) ? deg[i] : 0;
        s[tid] = v;
        __syncthreads();
        for (int d = 1; d < 256; d <<= 1) {
            const int t = (tid >= d) ? s[tid - d] : 0;
            __syncthreads();
            s[tid] += t;
            __syncthreads();
        }
        const int o = boff[pass * NB + blockIdx.x] + s[tid] - v;
        if (i < NN) { off[i] = o; cur[i] = o; }
        if (i == NN - 1) off[NN] = NE;
        __syncthreads();
    }
}

// per-node cursor scatter: 100K cursor addresses, ~26 atomics each (low
// contention). 8 independent chains/thread — latency-bound kernel.
__global__ void __launch_bounds__(256)
k_fill(const int* __restrict__ ei, int* __restrict__ cur_in, int* __restrict__ cur_out,
       int* __restrict__ csr_in, int* __restrict__ csr_out)
{
    const int base = (blockIdx.x * 256 + threadIdx.x) * 8;   // grid = NE/2048
    int s[8], d[8], p[8], q[8];
#pragma unroll
    for (int k = 0; k < 8; ++k) s[k] = ei[base + k];
#pragma unroll
    for (int k = 0; k < 8; ++k) d[k] = ei[NE + base + k];
#pragma unroll
    for (int k = 0; k < 8; ++k) p[k] = atomicAdd(&cur_out[s[k]], 1);
#pragma unroll
    for (int k = 0; k < 8; ++k) q[k] = atomicAdd(&cur_in[d[k]], 1);
#pragma unroll
    for (int k = 0; k < 8; ++k) csr_out[p[k]] = base + k;
#pragma unroll
    for (int k = 0; k < 8; ++k) csr_in[q[k]] = base + k;
}

// ---------------- encoder (+ degree histogram) ----------------
__global__ void __launch_bounds__(128)
k_enc(const float* __restrict__ x, const int* __restrict__ ei,
      const float* __restrict__ raw, const float* __restrict__ wenc,
      const float* __restrict__ benc, u16* __restrict__ hm,
      int* __restrict__ deg_in, int* __restrict__ deg_out)
{
    __shared__ alignas(16) u16 tile[WAVES][64 * LDP];
    const int w = threadIdx.x >> 6, lane = threadIdx.x & 63;

    for (int it = 0; it < EDGE_ITERS; ++it) {
        const int tileId = (it * EDGE_BLOCKS + blockIdx.x) * WAVES + w;
        const int e0 = tileId * 64;

        const int ms = ei[e0 + lane];
        const int md = ei[NE + e0 + lane];
        atomicAdd(&deg_out[ms], 1);                    // fused histogram
        atomicAdd(&deg_in[md], 1);

        float f[27];
#pragma unroll
        for (int j = 0; j < 13; ++j) f[j]      = x[ms * 13 + j];
#pragma unroll
        for (int j = 0; j < 13; ++j) f[13 + j] = x[md * 13 + j];
        f[26] = raw[e0 + lane];

        float acc[64];
#pragma unroll
        for (int c = 0; c < 64; ++c) acc[c] = benc[c];
        for (int k = 0; k < 27; ++k) {
            const float vk = f[k];
#pragma unroll
            for (int c = 0; c < 64; ++c) acc[c] += vk * wenc[k * 64 + c];
        }
#pragma unroll
        for (int c = 0; c < 64; ++c) tile[w][lane * LDP + c] = f2bf(lrelu(acc[c]));
        // wave-private LDS, lockstep wave64: no barrier. channel-major store.
        for (int i = 0; i < 64; ++i)
            hm[(size_t)(e0 + i) * 64 + lane] = tile[w][i * LDP + lane];
    }
}

// ---------------- per-node aggregate + transform: t = mean(h rows) @ W ----------------
__global__ void __launch_bounds__(256)
k_agg(const u16* __restrict__ hm,
      const int* __restrict__ off_in, const int* __restrict__ csr_in,
      const int* __restrict__ off_out, const int* __restrict__ csr_out,
      const float* __restrict__ w_in, const float* __restrict__ w_out,
      float* __restrict__ t_in, float* __restrict__ t_out)
{
    __shared__ float m[4][64];
    const int w = threadIdx.x >> 6, lane = threadIdx.x & 63;
    const int node = blockIdx.x * 4 + w;               // grid*4 == NN exactly
    const int rg = lane >> 3;                          // row slot in 8-batch
    const int co = (lane & 7) * 8;                     // channel octet base

    for (int pass = 0; pass < 2; ++pass) {
        const int* off = pass ? off_out : off_in;
        const int* csr = pass ? csr_out : csr_in;
        const float* wp = pass ? w_out : w_in;
        float* tp       = pass ? t_out : t_in;

        const int b0 = off[node], b1 = off[node + 1];
        float fa[8], fb[8];
#pragma unroll
        for (int c = 0; c < 8; ++c) { fa[c] = 0.f; fb[c] = 0.f; }

        int j = b0;
        for (; j + 16 <= b1; j += 16) {                // 16 rows in flight
            const int ea = csr[j + rg];
            const int eb = csr[j + 8 + rg];
            const short8 va = *(const short8*)(hm + (size_t)ea * 64 + co);
            const short8 vb = *(const short8*)(hm + (size_t)eb * 64 + co);
#pragma unroll
            for (int c = 0; c < 8; ++c) fa[c] += bf2f((u16)va[c]);
#pragma unroll
            for (int c = 0; c < 8; ++c) fb[c] += bf2f((u16)vb[c]);
        }
        for (; j < b1; j += 8) {                       // tail, predicated
            const int jj = j + rg;
            const int idx = jj < b1 ? jj : b0;
            const float fl = jj < b1 ? 1.f : 0.f;
            const int e = csr[idx];
            const short8 v = *(const short8*)(hm + (size_t)e * 64 + co);
#pragma unroll
            for (int c = 0; c < 8; ++c) fa[c] += fl * bf2f((u16)v[c]);
        }
#pragma unroll
        for (int c = 0; c < 8; ++c) fa[c] += fb[c];
#pragma unroll
        for (int d = 8; d < 64; d <<= 1)
#pragma unroll
            for (int c = 0; c < 8; ++c) fa[c] += __shfl_xor(fa[c], d, 64);

        const int deg = b1 - b0;
        const float inv = 1.0f / (float)(deg > 0 ? deg : 1);
        if (lane < 8) {
#pragma unroll
            for (int c = 0; c < 8; ++c) m[w][lane * 8 + c] = fa[c] * inv;
        }
        float acc = 0.f;
        for (int k = 0; k < 64; ++k) acc += m[w][k] * wp[k * 64 + lane];
        tp[(size_t)node * 64 + lane] = acc;
    }
}

// ---------------- conv edge update (layers 1,2), MFMA, no LDS tile ----------------
__global__ void __launch_bounds__(128, 4)
k_edge(const float* __restrict__ wself, const float* __restrict__ bself,
       const float* __restrict__ t_in, const float* __restrict__ t_out,
       const int* __restrict__ ei, u16* __restrict__ hm)
{
    __shared__ int sidx[WAVES][64], didx[WAVES][64];
    const int w = threadIdx.x >> 6, lane = threadIdx.x & 63;
    const int c16 = lane & 15, q4 = lane >> 4;

    short8 wf[2][4];                                   // Wself bf16 frags, resident
    float bias[4];
#pragma unroll
    for (int ks = 0; ks < 2; ++ks)
#pragma unroll
        for (int nt = 0; nt < 4; ++nt)
            wf[ks][nt] = bfrag(wself, 64, nt * 16 + c16, ks * 32 + q4 * 8);
#pragma unroll
    for (int nt = 0; nt < 4; ++nt) bias[nt] = bself[nt * 16 + c16];

    for (int it = 0; it < EDGE_ITERS; ++it) {
        const int tileId = (it * EDGE_BLOCKS + blockIdx.x) * WAVES + w;
        const int e0 = tileId * 64;
        sidx[w][lane] = ei[e0 + lane];                 // wave-private, lockstep
        didx[w][lane] = ei[NE + e0 + lane];

#pragma unroll
        for (int mt = 0; mt < 4; ++mt) {
            // A-frags for rows mt*16+c16 (disjoint from rows stored below)
            const short8* ap = (const short8*)(hm + (size_t)(e0 + mt * 16 + c16) * 64 + q4 * 8);
            const short8 a0 = ap[0];
            const short8 a1 = ap[4];
            floatx4 acc[4];
#pragma unroll
            for (int nt = 0; nt < 4; ++nt) acc[nt] = (floatx4)(0.0f);
#pragma unroll
            for (int nt = 0; nt < 4; ++nt) {
                acc[nt] = MFMA16(a0, wf[0][nt], acc[nt]);
                acc[nt] = MFMA16(a1, wf[1][nt], acc[nt]);
            }
            // t gathers for rows mt*16+q4*4+r (C-layout rows of this wave)
            float tv[4][4], uv[4][4];
#pragma unroll
            for (int r = 0; r < 4; ++r) {
                const int s = sidx[w][mt * 16 + q4 * 4 + r];
#pragma unroll
                for (int nt = 0; nt < 4; ++nt)
                    tv[r][nt] = t_in[(size_t)s * 64 + nt * 16 + c16];
            }
#pragma unroll
            for (int r = 0; r < 4; ++r) {
                const int d = didx[w][mt * 16 + q4 * 4 + r];
#pragma unroll
                for (int nt = 0; nt < 4; ++nt)
                    uv[r][nt] = t_out[(size_t)d * 64 + nt * 16 + c16];
            }
#pragma unroll
            for (int nt = 0; nt < 4; ++nt)
#pragma unroll
                for (int r = 0; r < 4; ++r) {
                    const int row = mt * 16 + q4 * 4 + r;
                    const float v = acc[nt][r] + bias[nt] + tv[r][nt] + uv[r][nt];
                    hm[(size_t)(e0 + row) * 64 + nt * 16 + c16] = f2bf(lrelu(v));
                }
        }
    }
}

// ---------------- conv3 + MLP head fused, MFMA ----------------
__global__ void __launch_bounds__(128, 2)
k_edge_mlp(const float* __restrict__ wself, const float* __restrict__ bself,
           const float* __restrict__ t_in, const float* __restrict__ t_out,
           const int* __restrict__ ei, const u16* __restrict__ hm,
           const float* __restrict__ w1, const float* __restrict__ b1,
           const float* __restrict__ w2, const float* __restrict__ b2,
           const float* __restrict__ w3, const float* __restrict__ b3,
           const float* __restrict__ w4, const float* __restrict__ b4,
           float* __restrict__ out)
{
    __shared__ alignas(16) u16 tile[WAVES][64 * LDP];
    __shared__ int sidx[WAVES][64], didx[WAVES][64];
    const int w = threadIdx.x >> 6, lane = threadIdx.x & 63;
    const int c16 = lane & 15, q4 = lane >> 4;

    short8 wfS[2][4], wf1[2][4], wf2[2][4], wf3[2][2];
    float bS[4], bv1[4], bv2[4], bv3[2];
#pragma unroll
    for (int ks = 0; ks < 2; ++ks) {
#pragma unroll
        for (int nt = 0; nt < 4; ++nt) {
            wfS[ks][nt] = bfrag(wself, 64, nt * 16 + c16, ks * 32 + q4 * 8);
            wf1[ks][nt] = bfrag(w1,    64, nt * 16 + c16, ks * 32 + q4 * 8);
            wf2[ks][nt] = bfrag(w2,    64, nt * 16 + c16, ks * 32 + q4 * 8);
        }
#pragma unroll
        for (int nt = 0; nt < 2; ++nt)
            wf3[ks][nt] = bfrag(w3, 32, nt * 16 + c16, ks * 32 + q4 * 8);
    }
#pragma unroll
    for (int nt = 0; nt < 4; ++nt) { bS[nt] = bself[nt*16+c16]; bv1[nt] = b1[nt*16+c16]; bv2[nt] = b2[nt*16+c16]; }
#pragma unroll
    for (int nt = 0; nt < 2; ++nt) bv3[nt] = b3[nt * 16 + c16];
    const float w4a = w4[c16], w4b = w4[16 + c16], b4v = b4[0];

    for (int it = 0; it < EDGE_ITERS; ++it) {
        const int tileId = (it * EDGE_BLOCKS + blockIdx.x) * WAVES + w;
        const int e0 = tileId * 64;
        sidx[w][lane] = ei[e0 + lane];
        didx[w][lane] = ei[NE + e0 + lane];

        // conv3: MFMA + direct t-add in C-layout, h3 -> LDS tile (one rounding)
#pragma unroll
        for (int mt = 0; mt < 4; ++mt) {
            const short8* ap = (const short8*)(hm + (size_t)(e0 + mt * 16 + c16) * 64 + q4 * 8);
            const short8 a0 = ap[0];
            const short8 a1 = ap[4];
            floatx4 acc[4];
#pragma unroll
            for (int nt = 0; nt < 4; ++nt) acc[nt] = (floatx4)(0.0f);
#pragma unroll
            for (int nt = 0; nt < 4; ++nt) {
                acc[nt] = MFMA16(a0, wfS[0][nt], acc[nt]);
                acc[nt] = MFMA16(a1, wfS[1][nt], acc[nt]);
            }
            float tv[4][4], uv[4][4];
#pragma unroll
            for (int r = 0; r < 4; ++r) {
                const int s = sidx[w][mt * 16 + q4 * 4 + r];
#pragma unroll
                for (int nt = 0; nt < 4; ++nt)
                    tv[r][nt] = t_in[(size_t)s * 64 + nt * 16 + c16];
            }
#pragma unroll
            for (int r = 0; r < 4; ++r) {
                const int d = didx[w][mt * 16 + q4 * 4 + r];
#pragma unroll
                for (int nt = 0; nt < 4; ++nt)
                    uv[r][nt] = t_out[(size_t)d * 64 + nt * 16 + c16];
            }
#pragma unroll
            for (int nt = 0; nt < 4; ++nt)
#pragma unroll
                for (int r = 0; r < 4; ++r) {
                    const int row = mt * 16 + q4 * 4 + r;
                    const float v = acc[nt][r] + bS[nt] + tv[r][nt] + uv[r][nt];
                    tile[w][row * LDP + nt * 16 + c16] = f2bf(lrelu(v));
                }
        }

        floatx4 acc[4][4];
        // MLP L1 (tile -> tile)
#pragma unroll
        for (int mt = 0; mt < 4; ++mt)
#pragma unroll
            for (int nt = 0; nt < 4; ++nt) acc[mt][nt] = (floatx4)(0.0f);
        mm_tile(tile[w], wf1, acc, c16, q4);
#pragma unroll
        for (int mt = 0; mt < 4; ++mt)
#pragma unroll
            for (int nt = 0; nt < 4; ++nt)
#pragma unroll
                for (int r = 0; r < 4; ++r)
                    tile[w][(mt * 16 + q4 * 4 + r) * LDP + nt * 16 + c16] =
                        f2bf(lrelu(acc[mt][nt][r] + bv1[nt]));

        // MLP L2
#pragma unroll
        for (int mt = 0; mt < 4; ++mt)
#pragma unroll
            for (int nt = 0; nt < 4; ++nt) acc[mt][nt] = (floatx4)(0.0f);
        mm_tile(tile[w], wf2, acc, c16, q4);
#pragma unroll
        for (int mt = 0; mt < 4; ++mt)
#pragma unroll
            for (int nt = 0; nt < 4; ++nt)
#pragma unroll
                for (int r = 0; r < 4; ++r)
                    tile[w][(mt * 16 + q4 * 4 + r) * LDP + nt * 16 + c16] =
                        f2bf(lrelu(acc[mt][nt][r] + bv2[nt]));

        // MLP L3: 64 -> 32 (acc in registers)
        floatx4 a3[4][2];
#pragma unroll
        for (int mt = 0; mt < 4; ++mt)
#pragma unroll
            for (int nt = 0; nt < 2; ++nt) a3[mt][nt] = (floatx4)(0.0f);
#pragma unroll
        for (int mt = 0; mt < 4; ++mt) {
            const short8 a0 = *(const short8*)(tile[w] + (mt * 16 + c16) * LDP + q4 * 8);
            const short8 a1 = *(const short8*)(tile[w] + (mt * 16 + c16) * LDP + 32 + q4 * 8);
#pragma unroll
            for (int nt = 0; nt < 2; ++nt) {
                a3[mt][nt] = MFMA16(a0, wf3[0][nt], a3[mt][nt]);
                a3[mt][nt] = MFMA16(a1, wf3[1][nt], a3[mt][nt]);
            }
        }
        // MLP L4 in registers: butterfly over c16 (no LDS, no bank conflicts)
#pragma unroll
        for (int mt = 0; mt < 4; ++mt)
#pragma unroll
            for (int r = 0; r < 4; ++r) {
                float p = lrelu(a3[mt][0][r] + bv3[0]) * w4a
                        + lrelu(a3[mt][1][r] + bv3[1]) * w4b;
                p += __shfl_xor(p, 1, 64);
                p += __shfl_xor(p, 2, 64);
                p += __shfl_xor(p, 4, 64);
                p += __shfl_xor(p, 8, 64);
                if (c16 == 0) out[e0 + mt * 16 + q4 * 4 + r] = p + b4v;
            }
    }
}

extern "C" void kernel_launch(void* const* d_in, const int* in_sizes, int n_in,
                              void* d_out, int out_size, void* d_ws, size_t ws_size,
                              hipStream_t stream)
{
    const float* x      = (const float*)d_in[0];
    const int*   ei     = (const int*)  d_in[1];
    const float* raw    = (const float*)d_in[2];
    const float* wenc   = (const float*)d_in[3];
    const float* benc   = (const float*)d_in[4];
    const float* wself1 = (const float*)d_in[5];
    const float* bself1 = (const float*)d_in[6];
    const float* win1   = (const float*)d_in[7];
    const float* wout1  = (const float*)d_in[8];
    const float* wself2 = (const float*)d_in[9];
    const float* bself2 = (const float*)d_in[10];
    const float* win2   = (const float*)d_in[11];
    const float* wout2  = (const float*)d_in[12];
    const float* wself3 = (const float*)d_in[13];
    const float* bself3 = (const float*)d_in[14];
    const float* win3   = (const float*)d_in[15];
    const float* wout3  = (const float*)d_in[16];
    const float* w1 = (const float*)d_in[17]; const float* b1 = (const float*)d_in[18];
    const float* w2 = (const float*)d_in[19]; const float* b2 = (const float*)d_in[20];
    const float* w3 = (const float*)d_in[21]; const float* b3 = (const float*)d_in[22];
    const float* w4 = (const float*)d_in[23]; const float* b4 = (const float*)d_in[24];

    // ws layout: t_in|t_out (fp32) · deg/cur/off/csr/bsum/boff (int) · hm (bf16)
    float* t_in    = (float*)d_ws;
    float* t_out   = t_in + (size_t)NN * 64;
    int*   deg_in  = (int*)(t_out + (size_t)NN * 64);
    int*   deg_out = deg_in + NN;
    int*   cur_in  = deg_out + NN;
    int*   cur_out = cur_in + NN;
    int*   off_in  = cur_out + NN;
    int*   off_out = off_in + OFFSZ;
    int*   csr_in  = off_out + OFFSZ;
    int*   csr_out = csr_in + NE;
    int*   bsum    = csr_out + NE;                     // 2*NB ints (512-pad)
    int*   boff    = bsum + 512;
    u16*   hm      = (u16*)(boff + 512);               // 16B-aligned

    hipMemsetAsync(deg_in, 0, (size_t)2 * NN * sizeof(int), stream);

    // encoder + fused degree histogram
    k_enc<<<EDGE_BLOCKS, 128, 0, stream>>>(x, ei, raw, wenc, benc, hm, deg_in, deg_out);

    // hierarchical scan + per-node-cursor CSR fill (R6 design, 8-wide ILP)
    k_bsum <<<NB, 256, 0, stream>>>(deg_in, deg_out, bsum);
    k_bscan<<<1,  256, 0, stream>>>(bsum, boff);
    k_bfill<<<NB, 256, 0, stream>>>(deg_in, deg_out, boff, off_in, off_out, cur_in, cur_out);
    k_fill<<<NE / 2048, 256, 0, stream>>>(ei, cur_in, cur_out, csr_in, csr_out);

    k_agg<<<NN / 4, 256, 0, stream>>>(hm, off_in, csr_in, off_out, csr_out,
                                      win1, wout1, t_in, t_out);
    k_edge<<<EDGE_BLOCKS, 128, 0, stream>>>(wself1, bself1, t_in, t_out, ei, hm);

    k_agg<<<NN / 4, 256, 0, stream>>>(hm, off_in, csr_in, off_out, csr_out,
                                      win2, wout2, t_in, t_out);
    k_edge<<<EDGE_BLOCKS, 128, 0, stream>>>(wself2, bself2, t_in, t_out, ei, hm);

    k_agg<<<NN / 4, 256, 0, stream>>>(hm, off_in, csr_in, off_out, csr_out,
                                      win3, wout3, t_in, t_out);
    k_edge_mlp<<<EDGE_BLOCKS, 128, 0, stream>>>(wself3, bself3, t_in, t_out, ei, hm,
                                                w1, b1, w2, b2, w3, b3, w4, b4,
                                                (float*)d_out);
}